// Round 3
// baseline (107.897 us; speedup 1.0000x reference)
//
#include <hip/hip_runtime.h>
#include <hip/hip_bf16.h>

// BATCH=512, INPUT_SIZE=64, ALPHA_DIM=64
// out[b,:] = log( E_0 E_1 ... E_62 p ), E_t = sigma(+-theta_t) col-scaled by
// softmax(u_t); variant per (b,t) from ballot mask of x.
//
// Strategy: 4 waves/batch; wave w computes P_w^T = (E_{16w}...E_{16w+15})^T
// via chained MFMA matmats (A = E_t^T precomputed bf16 frags, B = running
// product rebuilt from C regs with a lane^32 parity exchange). Then a 4-step
// matvec relay through LDS combines segments with p. Linear space throughout
// (values >= ~1e-36 >> f32/bf16 min normal); single log at the end.

#define NSTEP 63

typedef __attribute__((ext_vector_type(8)))  short short8;
typedef __attribute__((ext_vector_type(16))) float f32x16;

union U8 { short8 v; unsigned u[4]; unsigned short s[8]; };

static __device__ __forceinline__ unsigned short bf16b(float f) {
  union { __hip_bfloat16 h; unsigned short u; } cv;
  cv.h = __float2bfloat16(f);
  return cv.u;
}
static __device__ __forceinline__ unsigned pack2(float a, float b) {
  return (unsigned)bf16b(a) | ((unsigned)bf16b(b) << 16);
}

// ---------------- precompute: A-fragments of E_t^T, bf16 ----------------
// AF[((t*2+v)*8 + ti*4 + kc)*64 + lane] : short8 (16B)
// element e of lane l: E^T[32ti + (l&31)][16kc + 8*(l>>5) + e]
//                    = sigma_v(theta_t[16kc+8hi+e][32ti+lo]) * pa_t[32ti+lo]
__global__ __launch_bounds__(256) void precompute_kernel(
    const float* __restrict__ theta, const float* __restrict__ ulpa,
    short8* __restrict__ AF, float* __restrict__ pvar) {
  int t = blockIdx.x >> 1, v = blockIdx.x & 1;
  __shared__ float tile[64][65];
  __shared__ float pa[64];
  int tid = threadIdx.x;

  const float4* th4 = (const float4*)(theta + t * 4096);
  #pragma unroll
  for (int k = 0; k < 4; ++k) {
    int i = tid + k * 256;
    float4 w = th4[i];
    int a = i >> 4;
    int j0 = (i & 15) * 4;
    tile[a][j0 + 0] = w.x;
    tile[a][j0 + 1] = w.y;
    tile[a][j0 + 2] = w.z;
    tile[a][j0 + 3] = w.w;
  }
  if (tid < 64) {
    float u = ulpa[t * 64 + tid];
    float m = u;
    #pragma unroll
    for (int o = 32; o >= 1; o >>= 1) m = fmaxf(m, __shfl_xor(m, o));
    float e = __expf(u - m);
    float s = e;
    #pragma unroll
    for (int o = 32; o >= 1; o >>= 1) s += __shfl_xor(s, o);
    pa[tid] = e / s;
  }
  __syncthreads();

  #pragma unroll
  for (int it = 0; it < 2; ++it) {
    int fid = tid + it * 256;       // 0..511 = (ti,kc,lane)
    int lane = fid & 63, g = fid >> 6;
    int ti = g >> 2, kc = g & 3;
    int lo = lane & 31, hi = lane >> 5;
    int rr = 32 * ti + lo;
    float w = pa[rr];
    U8 f;
    #pragma unroll
    for (int e = 0; e < 8; ++e) {
      float th = tile[16 * kc + 8 * hi + e][rr];
      float sg = 1.0f / (1.0f + __expf(-th));
      float val = (v ? sg : (1.0f - sg)) * w;
      f.s[e] = bf16b(val);
    }
    AF[((t * 2 + v) * 8 + ti * 4 + kc) * 64 + lane] = f.v;
  }

  if (blockIdx.x == 0 && tid < 64) {
    float th = theta[63 * 4096 + tid * 64 + 0];
    float sg = 1.0f / (1.0f + __expf(-th));
    pvar[64 + tid] = sg;          // x-bit 1
    pvar[tid] = 1.0f - sg;        // x-bit 0
  }
}

// ---------------- main: segment products via MFMA + combine ----------------
__global__ __launch_bounds__(256) void chain_mfma(
    const float* __restrict__ x, const short8* __restrict__ AF,
    const float* __restrict__ pvar, float* __restrict__ out) {
  int b = blockIdx.x, tid = threadIdx.x;
  int w = tid >> 6, lane = tid & 63, lo = lane & 31, hi = lane >> 5;
  unsigned long long mask = __ballot(x[b * 64 + lane] != 0.0f);

  __shared__ __align__(16) float r_lds[64];

  f32x16 C[2][2];   // C[ti][j] = running R = P^T, rows 8*(4ti+(r>>2))+4hi+(r&3), col 32j+lo

  int t0 = w * 16;
  int nst = (w < 3) ? 16 : 15;

  // ---- step 0: C = E_{t0}^T x I ----
  {
    int t = t0, v = (int)((mask >> t) & 1ull);
    const short8* Ab = AF + ((size_t)(t * 2 + v) * 8) * 64 + lane;
    short8 A[4][2];
    #pragma unroll
    for (int kc = 0; kc < 4; ++kc)
      #pragma unroll
      for (int ti = 0; ti < 2; ++ti)
        A[kc][ti] = Ab[(ti * 4 + kc) * 64];

    #pragma unroll
    for (int ti = 0; ti < 2; ++ti)
      #pragma unroll
      for (int j = 0; j < 2; ++j)
        #pragma unroll
        for (int r = 0; r < 16; ++r) C[ti][j][r] = 0.0f;

    #pragma unroll
    for (int kc = 0; kc < 4; ++kc)
      #pragma unroll
      for (int j = 0; j < 2; ++j) {
        U8 Bf;
        #pragma unroll
        for (int r = 0; r < 4; ++r) Bf.u[r] = 0u;
        int diff = 32 * j + lo - 16 * kc - 8 * hi;
        if (diff >= 0 && diff < 8) Bf.s[diff] = 0x3F80;  // bf16 1.0
        #pragma unroll
        for (int ti = 0; ti < 2; ++ti)
          C[ti][j] = __builtin_amdgcn_mfma_f32_32x32x16_bf16(
              A[kc][ti], Bf.v, C[ti][j], 0, 0, 0);
      }
  }

  // ---- steps 1..nst-1: C = E_t^T x C ----
  for (int s = 1; s < nst; ++s) {
    int t = t0 + s, v = (int)((mask >> t) & 1ull);
    const short8* Ab = AF + ((size_t)(t * 2 + v) * 8) * 64 + lane;
    short8 A[4][2];
    #pragma unroll
    for (int kc = 0; kc < 4; ++kc)
      #pragma unroll
      for (int ti = 0; ti < 2; ++ti)
        A[kc][ti] = Ab[(ti * 4 + kc) * 64];

    // Build B-frags from C: B rows 16kc+8hi+{0..7} of col 32j+lo.
    // Row block M=2kc+hi lives in C tile M>>2, regs 4*(M&3)+q; the 4hi'=0
    // half comes from hi=0 lanes, 4hi'=1 half from hi=1 lanes -> lane^32 swap.
    unsigned Bw[4][2][4];
    #pragma unroll
    for (int kc = 0; kc < 4; ++kc) {
      int Me = 2 * kc, Mo = 2 * kc + 1;
      int tie = Me >> 2, me = Me & 3;
      int tio = Mo >> 2, mo = Mo & 3;
      #pragma unroll
      for (int j = 0; j < 2; ++j) {
        unsigned pe0 = pack2(C[tie][j][4 * me + 0], C[tie][j][4 * me + 1]);
        unsigned pe1 = pack2(C[tie][j][4 * me + 2], C[tie][j][4 * me + 3]);
        unsigned po0 = pack2(C[tio][j][4 * mo + 0], C[tio][j][4 * mo + 1]);
        unsigned po1 = pack2(C[tio][j][4 * mo + 2], C[tio][j][4 * mo + 3]);
        unsigned s0 = hi ? pe0 : po0;           // send partner what it needs
        unsigned s1 = hi ? pe1 : po1;
        unsigned r0 = (unsigned)__shfl_xor((int)s0, 32);
        unsigned r1 = (unsigned)__shfl_xor((int)s1, 32);
        Bw[kc][j][0] = hi ? r0 : pe0;           // rows +0..+3 (from hi'=0)
        Bw[kc][j][1] = hi ? r1 : pe1;
        Bw[kc][j][2] = hi ? po0 : r0;           // rows +4..+7 (from hi'=1)
        Bw[kc][j][3] = hi ? po1 : r1;
      }
    }

    #pragma unroll
    for (int ti = 0; ti < 2; ++ti)
      #pragma unroll
      for (int j = 0; j < 2; ++j)
        #pragma unroll
        for (int r = 0; r < 16; ++r) C[ti][j][r] = 0.0f;

    #pragma unroll
    for (int kc = 0; kc < 4; ++kc)
      #pragma unroll
      for (int j = 0; j < 2; ++j) {
        U8 Bf;
        #pragma unroll
        for (int r = 0; r < 4; ++r) Bf.u[r] = Bw[kc][j][r];
        #pragma unroll
        for (int ti = 0; ti < 2; ++ti)
          C[ti][j] = __builtin_amdgcn_mfma_f32_32x32x16_bf16(
              A[kc][ti], Bf.v, C[ti][j], 0, 0, 0);
      }
  }

  // ---- combine: r = P0 (P1 (P2 (P3 p))) ----
  __syncthreads();
  if (w == 3) r_lds[lane] = pvar[(int)((mask >> 63) & 1ull) * 64 + lane];
  __syncthreads();

  for (int ww = 3; ww >= 0; --ww) {
    if (w == ww) {
      float4 rv[8];
      #pragma unroll
      for (int M = 0; M < 8; ++M)
        rv[M] = *(const float4*)&r_lds[8 * M + 4 * hi];
      float y0 = 0.0f, y1 = 0.0f;
      #pragma unroll
      for (int M = 0; M < 8; ++M) {
        int ti = M >> 2, m = M & 3;
        y0 = fmaf(C[ti][0][4 * m + 0], rv[M].x, y0);
        y0 = fmaf(C[ti][0][4 * m + 1], rv[M].y, y0);
        y0 = fmaf(C[ti][0][4 * m + 2], rv[M].z, y0);
        y0 = fmaf(C[ti][0][4 * m + 3], rv[M].w, y0);
        y1 = fmaf(C[ti][1][4 * m + 0], rv[M].x, y1);
        y1 = fmaf(C[ti][1][4 * m + 1], rv[M].y, y1);
        y1 = fmaf(C[ti][1][4 * m + 2], rv[M].z, y1);
        y1 = fmaf(C[ti][1][4 * m + 3], rv[M].w, y1);
      }
      y0 += __shfl_xor(y0, 32);
      y1 += __shfl_xor(y1, 32);
      if (ww == 0) {
        if (hi == 0) out[b * 64 + lo] = logf(y0);
        else         out[b * 64 + 32 + lo] = logf(y1);
      } else {
        if (hi == 0) r_lds[lo] = y0;
        else         r_lds[32 + lo] = y1;
      }
    }
    __syncthreads();
  }
}

extern "C" void kernel_launch(void* const* d_in, const int* in_sizes, int n_in,
                              void* d_out, int out_size, void* d_ws, size_t ws_size,
                              hipStream_t stream) {
  const float* x     = (const float*)d_in[0];  // (512, 64)
  const float* theta = (const float*)d_in[1];  // (1, 64, 64, 64)
  const float* ulpa  = (const float*)d_in[2];  // (1, 63, 1, 64)
  float* out = (float*)d_out;                  // (512, 64, 1)

  short8* AF  = (short8*)d_ws;                         // 63*2*8*64 frags (1 MB)
  float* pvar = (float*)((char*)d_ws + NSTEP * 2 * 8 * 64 * 16);

  hipLaunchKernelGGL(precompute_kernel, dim3(NSTEP * 2), dim3(256), 0, stream,
                     theta, ulpa, AF, pvar);
  hipLaunchKernelGGL(chain_mfma, dim3(512), dim3(256), 0, stream,
                     x, AF, pvar, out);
}

// Round 4
// 100.870 us; speedup vs baseline: 1.0697x; 1.0697x over previous
//
#include <hip/hip_runtime.h>
#include <hip/hip_bf16.h>

// BATCH=512, INPUT_SIZE=64, ALPHA_DIM=64
// out[b,:] = log( M_0 M_1 ... M_62 p ),  M_t[a][j] = sigma_v(theta_t[a][j]) * pa_t[j]
// v = x[b][t];  p[k] = sigma_{x[b][63]}(theta_63[k][0]).
//
// Plan: group t into 15 quads (t=4g..4g+3) + 1 triple (t=60..62). Precompute
// ALL variant products (15*16 + 8 = 248 matrices, fp32, 4 MB — L2-resident)
// with a 1-wave-per-matrix MFMA kernel (fragment layouts validated in R3).
// Per-batch chain is then 16 matvec steps (R2's STEP structure).
//
// Chain layout per matrix: o = (j>>2)*256 + a*4 + (j&3)
//   => lane a loads float4 at Qm4[g*64 + a] covering j=4g..4g+3 (coalesced)

#define NSTEP 63

typedef __attribute__((ext_vector_type(8)))  short short8;
typedef __attribute__((ext_vector_type(16))) float f32x16;

union U8 { short8 v; unsigned u[4]; unsigned short s[8]; };

static __device__ __forceinline__ unsigned short bf16b(float f) {
  union { __hip_bfloat16 h; unsigned short u; } cv;
  cv.h = __float2bfloat16(f);
  return cv.u;
}
static __device__ __forceinline__ unsigned pack2(float a, float b) {
  return (unsigned)bf16b(a) | ((unsigned)bf16b(b) << 16);
}

// ---------------- precompute: one wave per (group, variant) product ----------
// bid 0..239: g=bid>>4, v=bid&15, t0=4g, nt=4; bid 240..247: triple, v=bid-240.
// M = E_{t0}^{b0} E_{t0+1}^{b1} ... , b_i=(v>>i)&1.  E LDS bf16, XOR-swizzled
// rows (byte ^= (row&7)<<4) to kill the stride-128B bank conflict on A-frag
// ds_read_b128 (G4 / T2).
__global__ __launch_bounds__(64) void quad_kernel(
    const float* __restrict__ theta, const float* __restrict__ ulpa,
    float* __restrict__ Mq) {
  __shared__ __align__(16) unsigned short Elds[4 * 4096];
  __shared__ float paL[4][64];

  int bid = blockIdx.x;
  int lane = threadIdx.x, lo = lane & 31, hi = lane >> 5;
  int v, nt, t0;
  if (bid < 240) { v = bid & 15; nt = 4; t0 = 4 * (bid >> 4); }
  else           { v = bid - 240; nt = 3; t0 = 60; }

  // pa_t = softmax(ulpa[t])
  for (int i = 0; i < nt; ++i) {
    float uu = ulpa[(t0 + i) * 64 + lane];
    float m = uu;
    #pragma unroll
    for (int o = 32; o >= 1; o >>= 1) m = fmaxf(m, __shfl_xor(m, o));
    float e = __expf(uu - m);
    float s = e;
    #pragma unroll
    for (int o = 32; o >= 1; o >>= 1) s += __shfl_xor(s, o);
    paL[i][lane] = e / s;
  }

  // E_i[row][col] = sigma_{b_i}(theta[row][col]) * pa[col], bf16, swizzled
  for (int i = 0; i < nt; ++i) {
    int vb = (v >> i) & 1;
    const float4* th4 = (const float4*)(theta + (t0 + i) * 4096);
    #pragma unroll
    for (int it = 0; it < 16; ++it) {
      int q = it * 64 + lane;
      int row = q >> 4, c = q & 15;
      float4 tv = th4[q];
      float4 pv = *(const float4*)&paL[i][4 * c];
      float s0 = 1.0f / (1.0f + __expf(-tv.x));
      float s1 = 1.0f / (1.0f + __expf(-tv.y));
      float s2 = 1.0f / (1.0f + __expf(-tv.z));
      float s3 = 1.0f / (1.0f + __expf(-tv.w));
      if (!vb) { s0 = 1.0f - s0; s1 = 1.0f - s1; s2 = 1.0f - s2; s3 = 1.0f - s3; }
      unsigned w0 = pack2(s0 * pv.x, s1 * pv.y);
      unsigned w1 = pack2(s2 * pv.z, s3 * pv.w);
      unsigned byteoff = (unsigned)(i * 8192) +
          (((unsigned)(row * 128 + 8 * c)) ^ ((unsigned)(row & 7) << 4));
      *reinterpret_cast<uint2*>(reinterpret_cast<char*>(Elds) + byteoff) =
          make_uint2(w0, w1);
    }
  }

  // first B-frags = E_{nt-1}: B[k=16kc+8hi+e][n=32j+lo]
  U8 Bf[4][2];
  {
    int ib = nt - 1;
    #pragma unroll
    for (int kc = 0; kc < 4; ++kc)
      #pragma unroll
      for (int j = 0; j < 2; ++j)
        #pragma unroll
        for (int e = 0; e < 8; ++e) {
          int krow = 16 * kc + 8 * hi + e;
          unsigned byteoff = (unsigned)(ib * 8192) +
              (((unsigned)(krow * 128 + (32 * j + lo) * 2)) ^
               ((unsigned)(krow & 7) << 4));
          Bf[kc][j].s[e] =
              *reinterpret_cast<const unsigned short*>(
                  reinterpret_cast<const char*>(Elds) + byteoff);
        }
  }

  f32x16 C[2][2];
  for (int im = nt - 2; im >= 0; --im) {
    // A-frags = E_im: A[m=32ti+lo][k=16kc+8hi+e], contiguous 16B per frag
    short8 A[4][2];
    #pragma unroll
    for (int kc = 0; kc < 4; ++kc)
      #pragma unroll
      for (int ti = 0; ti < 2; ++ti) {
        int arow = 32 * ti + lo;
        unsigned byteoff = (unsigned)(im * 8192) +
            (((unsigned)(arow * 128 + (16 * kc + 8 * hi) * 2)) ^
             ((unsigned)(arow & 7) << 4));
        A[kc][ti] = *reinterpret_cast<const short8*>(
            reinterpret_cast<const char*>(Elds) + byteoff);
      }

    #pragma unroll
    for (int ti = 0; ti < 2; ++ti)
      #pragma unroll
      for (int j = 0; j < 2; ++j)
        #pragma unroll
        for (int r = 0; r < 16; ++r) C[ti][j][r] = 0.0f;

    #pragma unroll
    for (int kc = 0; kc < 4; ++kc)
      #pragma unroll
      for (int j = 0; j < 2; ++j)
        #pragma unroll
        for (int ti = 0; ti < 2; ++ti)
          C[ti][j] = __builtin_amdgcn_mfma_f32_32x32x16_bf16(
              A[kc][ti], Bf[kc][j].v, C[ti][j], 0, 0, 0);

    if (im > 0) {
      // rebuild B-frags from C (validated lane^32 parity exchange, R3)
      #pragma unroll
      for (int kc = 0; kc < 4; ++kc) {
        int Me = 2 * kc, Mo = 2 * kc + 1;
        int tie = Me >> 2, me = Me & 3;
        int tio = Mo >> 2, mo = Mo & 3;
        #pragma unroll
        for (int j = 0; j < 2; ++j) {
          unsigned pe0 = pack2(C[tie][j][4 * me + 0], C[tie][j][4 * me + 1]);
          unsigned pe1 = pack2(C[tie][j][4 * me + 2], C[tie][j][4 * me + 3]);
          unsigned po0 = pack2(C[tio][j][4 * mo + 0], C[tio][j][4 * mo + 1]);
          unsigned po1 = pack2(C[tio][j][4 * mo + 2], C[tio][j][4 * mo + 3]);
          unsigned s0 = hi ? pe0 : po0;
          unsigned s1 = hi ? pe1 : po1;
          unsigned r0 = (unsigned)__shfl_xor((int)s0, 32);
          unsigned r1 = (unsigned)__shfl_xor((int)s1, 32);
          Bf[kc][j].u[0] = hi ? r0 : pe0;
          Bf[kc][j].u[1] = hi ? r1 : pe1;
          Bf[kc][j].u[2] = hi ? po0 : r0;
          Bf[kc][j].u[3] = hi ? po1 : r1;
        }
      }
    }
  }

  // scatter C (fp32) into chain layout: o=(n>>2)*256 + m*4 + (n&3)
  float* outp = Mq + (size_t)bid * 4096;
  #pragma unroll
  for (int ti = 0; ti < 2; ++ti)
    #pragma unroll
    for (int j = 0; j < 2; ++j)
      #pragma unroll
      for (int r = 0; r < 16; ++r) {
        int m = 32 * ti + (r & 3) + 8 * (r >> 2) + 4 * hi;
        int n = 32 * j + lo;
        outp[(n >> 2) * 256 + m * 4 + (n & 3)] = C[ti][j][r];
      }
}

// ---------------- chain: 16 matvec steps per batch ----------------
__global__ __launch_bounds__(64) void chain_kernel(
    const float* __restrict__ x, const float* __restrict__ theta,
    const float* __restrict__ Mq, float* __restrict__ out) {
  int b = blockIdx.x;     // 0..511
  int lane = threadIdx.x; // 0..63

  unsigned long long mask = __ballot(x[b * 64 + lane] != 0.0f);

  __shared__ __align__(16) float u_lds[64];

  // u = p: sigma variant of theta[63][lane][0]
  float th = theta[63 * 4096 + lane * 64];
  float sg = 1.0f / (1.0f + __expf(-th));
  float u = ((mask >> 63) & 1ull) ? sg : (1.0f - sg);
  float acc = 0.0f;

#define GIDX(g) ((g) < 15 ? (g) * 16 + (int)((mask >> (4 * (g))) & 15ull) \
                          : 240 + (int)((mask >> 60) & 7ull))

  float4 qa[16], qb[16];
  {
    const float4* P = (const float4*)(Mq + (size_t)GIDX(15) * 4096);
    #pragma unroll
    for (int g = 0; g < 16; ++g) qa[g] = P[g * 64 + lane];
  }

  // One step: broadcast u via LDS (single wave, no barrier), prefetch group
  // PG into PREG, 64 FMAs on 4 independent accumulators.
  #define STEP(QREG, PG, PREG)                                              \
    {                                                                       \
      u_lds[lane] = u;                                                      \
      if ((PG) >= 0) {                                                      \
        const float4* P = (const float4*)(Mq + (size_t)GIDX(PG) * 4096);    \
        _Pragma("unroll")                                                   \
        for (int g = 0; g < 16; ++g) PREG[g] = P[g * 64 + lane];            \
      }                                                                     \
      float s0 = 0.f, s1 = 0.f, s2 = 0.f, s3 = 0.f;                         \
      _Pragma("unroll")                                                     \
      for (int g = 0; g < 16; g += 4) {                                     \
        float4 q0 = QREG[g + 0], q1 = QREG[g + 1];                          \
        float4 q2 = QREG[g + 2], q3 = QREG[g + 3];                          \
        float4 u0 = *(const float4*)&u_lds[(g + 0) * 4];                    \
        float4 u1 = *(const float4*)&u_lds[(g + 1) * 4];                    \
        float4 u2 = *(const float4*)&u_lds[(g + 2) * 4];                    \
        float4 u3 = *(const float4*)&u_lds[(g + 3) * 4];                    \
        s0 = fmaf(q0.x, u0.x, s0); s0 = fmaf(q0.y, u0.y, s0);               \
        s0 = fmaf(q0.z, u0.z, s0); s0 = fmaf(q0.w, u0.w, s0);               \
        s1 = fmaf(q1.x, u1.x, s1); s1 = fmaf(q1.y, u1.y, s1);               \
        s1 = fmaf(q1.z, u1.z, s1); s1 = fmaf(q1.w, u1.w, s1);               \
        s2 = fmaf(q2.x, u2.x, s2); s2 = fmaf(q2.y, u2.y, s2);               \
        s2 = fmaf(q2.z, u2.z, s2); s2 = fmaf(q2.w, u2.w, s2);               \
        s3 = fmaf(q3.x, u3.x, s3); s3 = fmaf(q3.y, u3.y, s3);               \
        s3 = fmaf(q3.z, u3.z, s3); s3 = fmaf(q3.w, u3.w, s3);               \
      }                                                                     \
      u = (s0 + s1) + (s2 + s3);                                            \
    }

  // apply groups g = 15 .. 0 (right-to-left product)
  #pragma unroll
  for (int gg = 15; gg >= 1; gg -= 2) {
    STEP(qa, gg - 1, qb);
    STEP(qb, gg - 2, qa);       // gg==1: PG=-1, no prefetch
    if (gg == 9) {              // after 8 applied steps; decay >= ~1e-23, safe
      float m = u;
      #pragma unroll
      for (int o = 32; o >= 1; o >>= 1) m = fmaxf(m, __shfl_xor(m, o));
      acc += __logf(m);
      u *= (1.0f / m);
    }
  }
  #undef STEP
  #undef GIDX

  out[b * 64 + lane] = logf(u) + acc;
}

extern "C" void kernel_launch(void* const* d_in, const int* in_sizes, int n_in,
                              void* d_out, int out_size, void* d_ws, size_t ws_size,
                              hipStream_t stream) {
  const float* x     = (const float*)d_in[0];  // (512, 64)
  const float* theta = (const float*)d_in[1];  // (1, 64, 64, 64)
  const float* ulpa  = (const float*)d_in[2];  // (1, 63, 1, 64)
  float* out = (float*)d_out;                  // (512, 64, 1)

  float* Mq = (float*)d_ws;                    // 248 * 4096 floats (~4 MB)

  hipLaunchKernelGGL(quad_kernel, dim3(248), dim3(64), 0, stream,
                     theta, ulpa, Mq);
  hipLaunchKernelGGL(chain_kernel, dim3(512), dim3(64), 0, stream,
                     x, theta, Mq, out);
}